// Round 1
// baseline (527.991 us; speedup 1.0000x reference)
//
#include <hip/hip_runtime.h>
#include <stdint.h>

typedef float  f32x4  __attribute__((ext_vector_type(4)));
typedef short  bf16x8 __attribute__((ext_vector_type(8)));

#define TYPES 10
#define D_IN  128
#define D_H1  512
#define D_H2  512
#define D_OUT 256

__device__ __forceinline__ unsigned short f2bf(float f) {
  union { float f; unsigned u; } v; v.f = f;
  unsigned u = v.u;
  return (unsigned short)((u + 0x7FFFu + ((u >> 16) & 1u)) >> 16);  // RTNE
}

__device__ __forceinline__ void async16(void* lds, const void* g) {
  __builtin_amdgcn_global_load_lds(
      (const __attribute__((address_space(1))) void*)g,
      (__attribute__((address_space(3))) void*)lds, 16, 0, 0);
}

// meta layout (ints): [0..9] counts, [16..26] padded offsets (offs[10]=total), [32..41] scatter cursors
__global__ void k_init(int* meta) {
  if (threadIdx.x < 48) meta[threadIdx.x] = 0;
}

__global__ void k_hist(const int* __restrict__ types, int n, int* __restrict__ meta) {
  __shared__ int lc[TYPES];
  if (threadIdx.x < TYPES) lc[threadIdx.x] = 0;
  __syncthreads();
  int i = blockIdx.x * 256 + threadIdx.x;
  if (i < n) atomicAdd(&lc[types[i]], 1);
  __syncthreads();
  if (threadIdx.x < TYPES && lc[threadIdx.x]) atomicAdd(&meta[threadIdx.x], lc[threadIdx.x]);
}

__global__ void k_scan(int* meta) {
  if (threadIdx.x == 0) {
    int off = 0;
    for (int t = 0; t < TYPES; ++t) {
      meta[16 + t] = off;
      off += ((meta[t] + 127) >> 7) << 7;   // pad each segment to 128 rows
    }
    meta[26] = off;                          // padded total
  }
}

__global__ void k_scatter(const int* __restrict__ types, int n,
                          int* __restrict__ meta, int* __restrict__ perm) {
  __shared__ int lc[TYPES], lbase[TYPES];
  if (threadIdx.x < TYPES) lc[threadIdx.x] = 0;
  __syncthreads();
  int i = blockIdx.x * 256 + threadIdx.x;
  int t = 0, loc = 0;
  bool ok = i < n;
  if (ok) { t = types[i]; loc = atomicAdd(&lc[t], 1); }
  __syncthreads();
  if (threadIdx.x < TYPES) {
    int c = lc[threadIdx.x];
    lbase[threadIdx.x] = c ? atomicAdd(&meta[32 + threadIdx.x], c) : 0;
  }
  __syncthreads();
  if (ok) perm[meta[16 + t] + lbase[t] + loc] = i;
}

// gather rows into sorted order, fp32 -> bf16; zero the padding rows
__global__ void k_gather(const float* __restrict__ x, const int* __restrict__ perm,
                         const int* __restrict__ meta, unsigned short* __restrict__ xs) {
  int p = blockIdx.x * 8 + (threadIdx.x >> 5);
  if (p >= meta[26]) return;
  int t = 0;
  while (p >= meta[17 + t]) t++;
  int e = (threadIdx.x & 31) * 4;
  unsigned short o0, o1, o2, o3;
  if (p - meta[16 + t] < meta[t]) {
    const float4 v = *(const float4*)(x + (size_t)perm[p] * D_IN + e);
    o0 = f2bf(v.x); o1 = f2bf(v.y); o2 = f2bf(v.z); o3 = f2bf(v.w);
  } else {
    o0 = o1 = o2 = o3 = 0;
  }
  *(ushort4*)(xs + (size_t)p * D_IN + e) = make_ushort4(o0, o1, o2, o3);
}

// W[t] (K x NOUT) fp32 -> Wt[t] (NOUT x K) bf16, 64x64 LDS tiles
__global__ void k_wtrans(const float* __restrict__ W, unsigned short* __restrict__ Wt,
                         int K, int NOUT) {
  int t = blockIdx.y;
  int ntn = NOUT >> 6;
  int kb = blockIdx.x / ntn, nb = blockIdx.x % ntn;
  __shared__ unsigned short tile[64][65];
  const float* src = W + (size_t)t * K * NOUT + (size_t)(kb * 64) * NOUT + nb * 64;
  int c = threadIdx.x & 63;
  int r0 = threadIdx.x >> 6;
  #pragma unroll
  for (int i = 0; i < 16; ++i) {
    int r = r0 * 16 + i;
    tile[r][c] = f2bf(src[(size_t)r * NOUT + c]);
  }
  __syncthreads();
  unsigned short* dst = Wt + (size_t)t * NOUT * K + (size_t)(nb * 64) * K + kb * 64;
  #pragma unroll
  for (int i = 0; i < 16; ++i) {
    int nn = r0 * 16 + i;
    dst[(size_t)nn * K + c] = tile[c][nn];
  }
}

// Grouped GEMM over sorted rows. A: [NPAD][K] bf16 row-major. Wt: [10][NOUT][K] bf16.
// 128x128 tile, BK=32, 4 waves (2x2) each computing 64x64 via 4x4 16x16x32 frags.
template <int K, int NOUT, bool RELU, bool FINAL>
__launch_bounds__(256)
__global__ void k_gemm(const unsigned short* __restrict__ A,
                       const unsigned short* __restrict__ Wt,
                       const float* __restrict__ bias,
                       unsigned short* __restrict__ H,
                       float* __restrict__ OUT,
                       const int* __restrict__ meta,
                       const int* __restrict__ perm) {
  __shared__ unsigned short As[128 * 32];
  __shared__ unsigned short Bs[128 * 32];
  int row0 = blockIdx.y * 128;
  if (row0 >= meta[26]) return;
  int t = 0;
  while (row0 >= meta[17 + t]) t++;          // segment offsets are multiples of 128
  int seg = meta[16 + t], cnt = meta[t];
  int tid = threadIdx.x, lane = tid & 63, wid = tid >> 6;
  int wr = (wid >> 1) * 64, wc = (wid & 1) * 64;
  int col0 = blockIdx.x * 128;
  const unsigned short* Ag = A + (size_t)row0 * K;
  const unsigned short* Bg = Wt + ((size_t)t * NOUT + col0) * K;

  f32x4 acc[4][4] = {};
  int r_ld = tid >> 2;            // row within 64-row chunk
  int k_ld = (tid & 3) * 8;       // bf16 element offset within 32-wide row
  int ldsbase = (tid & ~63) * 8;  // wave-uniform LDS element base (lane adds lane*16B)

  constexpr int nK = K / 32;
  for (int kt = 0; kt < nK; ++kt) {
    __syncthreads();              // previous compute done; safe to overwrite tiles
    #pragma unroll
    for (int i = 0; i < 2; ++i) {
      int r = i * 64 + r_ld;
      async16(As + i * 2048 + ldsbase, Ag + (size_t)r * K + kt * 32 + k_ld);
      async16(Bs + i * 2048 + ldsbase, Bg + (size_t)r * K + kt * 32 + k_ld);
    }
    __syncthreads();              // compiler drains vmcnt(0) before barrier

    int koff = (lane >> 4) * 8;
    int rA = lane & 15;
    bf16x8 a[4], b[4];
    #pragma unroll
    for (int m = 0; m < 4; ++m)
      a[m] = *(const bf16x8*)(As + (wr + m * 16 + rA) * 32 + koff);
    #pragma unroll
    for (int n = 0; n < 4; ++n)
      b[n] = *(const bf16x8*)(Bs + (wc + n * 16 + rA) * 32 + koff);
    #pragma unroll
    for (int m = 0; m < 4; ++m)
      #pragma unroll
      for (int n = 0; n < 4; ++n)
        acc[m][n] = __builtin_amdgcn_mfma_f32_16x16x32_bf16(a[m], b[n], acc[m][n], 0, 0, 0);
  }

  // epilogue: D mapping col=lane&15, row=(lane>>4)*4+e (measured, learn_hip m89/m91)
  int cA = lane & 15, rE = (lane >> 4) * 4;
  #pragma unroll
  for (int n = 0; n < 4; ++n) {
    int col = col0 + wc + n * 16 + cA;
    float bv = bias[t * NOUT + col];
    #pragma unroll
    for (int m = 0; m < 4; ++m) {
      int rb = row0 + wr + m * 16 + rE;
      #pragma unroll
      for (int e = 0; e < 4; ++e) {
        float v = acc[m][n][e] + bv;
        if (RELU) v = fmaxf(v, 0.f);
        if (!FINAL) {
          H[(size_t)(rb + e) * NOUT + col] = f2bf(v);
        } else {
          int r = rb + e;
          if (r - seg < cnt) OUT[(size_t)perm[r] * NOUT + col] = v;
        }
      }
    }
  }
}

extern "C" void kernel_launch(void* const* d_in, const int* in_sizes, int n_in,
                              void* d_out, int out_size, void* d_ws, size_t ws_size,
                              hipStream_t stream) {
  const float* x     = (const float*)d_in[0];
  const int*   types = (const int*)d_in[1];
  const float* W0    = (const float*)d_in[2];
  const float* b0    = (const float*)d_in[3];
  const float* W1    = (const float*)d_in[4];
  const float* b1    = (const float*)d_in[5];
  const float* W2    = (const float*)d_in[6];
  const float* b2    = (const float*)d_in[7];
  float* out = (float*)d_out;
  int n = in_sizes[1];
  int RB = (n + 127) / 128 + TYPES;       // worst-case padded row blocks
  size_t NPAD = (size_t)RB * 128;

  char* ws = (char*)d_ws;
  int* meta = (int*)ws;
  int* perm = (int*)(ws + 1024);
  size_t off = 1024 + NPAD * 4;
  off = (off + 255) & ~(size_t)255;
  unsigned short* wt0 = (unsigned short*)(ws + off); off += (size_t)TYPES * D_H1 * D_IN * 2;
  unsigned short* wt1 = (unsigned short*)(ws + off); off += (size_t)TYPES * D_H2 * D_H1 * 2;
  unsigned short* wt2 = (unsigned short*)(ws + off); off += (size_t)TYPES * D_OUT * D_H2 * 2;
  off = (off + 255) & ~(size_t)255;
  unsigned short* B1 = (unsigned short*)(ws + off); off += NPAD * 512 * 2;  // xs, later h2
  unsigned short* B2 = (unsigned short*)(ws + off); off += NPAD * 512 * 2;  // h1

  int hb = (n + 255) / 256;
  k_init<<<1, 64, 0, stream>>>(meta);
  k_hist<<<hb, 256, 0, stream>>>(types, n, meta);
  k_scan<<<1, 64, 0, stream>>>(meta);
  k_scatter<<<hb, 256, 0, stream>>>(types, n, meta, perm);
  k_gather<<<RB * 16, 256, 0, stream>>>(x, perm, meta, B1);
  k_wtrans<<<dim3((D_IN / 64) * (D_H1 / 64), TYPES), 256, 0, stream>>>(W0, wt0, D_IN, D_H1);
  k_wtrans<<<dim3((D_H1 / 64) * (D_H2 / 64), TYPES), 256, 0, stream>>>(W1, wt1, D_H1, D_H2);
  k_wtrans<<<dim3((D_H2 / 64) * (D_OUT / 64), TYPES), 256, 0, stream>>>(W2, wt2, D_H2, D_OUT);

  k_gemm<D_IN, D_H1, true,  false><<<dim3(D_H1 / 128, RB), 256, 0, stream>>>(B1, wt0, b0, B2, nullptr, meta, perm);
  k_gemm<D_H1, D_H2, true,  false><<<dim3(D_H2 / 128, RB), 256, 0, stream>>>(B2, wt1, b1, B1, nullptr, meta, perm);
  k_gemm<D_H2, D_OUT, false, true ><<<dim3(D_OUT / 128, RB), 256, 0, stream>>>(B1, wt2, b2, nullptr, out, meta, perm);
}